// Round 1
// 88.873 us; speedup vs baseline: 1.0054x; 1.0054x over previous
//
#include <hip/hip_runtime.h>
#include <hip/hip_bf16.h>

#define N_TOT 4096
#define D     512
#define BHALF 2048

// exp(2s) = 2^(s * 2*log2(e))
#define EXP2_SCALE 2.8853900817779268f
// exp(2*S_ii) for a normalized row (S_ii = 1 +- ~5e-3 in fp8; error in the
// final log is ~1e-5 -- negligible vs the 0.166 threshold)
#define E2 7.3890560989306495f

typedef __attribute__((ext_vector_type(4))) float floatx4;

#define AS_GLOBAL(p) ((const __attribute__((address_space(1))) void*)(p))
#define AS_LDS(p)    ((__attribute__((address_space(3))) void*)(p))

// s_waitcnt imm: vmcnt[3:0] | expcnt=7<<4 | lgkmcnt=15<<8 (ignore exp/lgkm)
#define WAITCNT_VM(n) (0xF70 | (n))

// ---------------- kernel 1: normalize rows, cast to fp8 e4m3 --------------
// 1024 blocks x 256 threads; one 64-lane wave per row, no LDS, no barrier.
// Also zeroes rowsum[] (ws is re-poisoned to 0xAA before every timed call).
__global__ void normalize_kernel(const float* __restrict__ z_i,
                                 const float* __restrict__ z_j,
                                 unsigned char* __restrict__ zn,
                                 float* __restrict__ rowsum) {
    const int wave = threadIdx.x >> 6, lane = threadIdx.x & 63;
    const int row = blockIdx.x * 4 + wave;
    const float* src = (row < BHALF) ? (z_i + (size_t)row * D)
                                     : (z_j + (size_t)(row - BHALF) * D);
    if (lane == 0) rowsum[row] = 0.0f;
    float4 v0 = ((const float4*)src)[lane];
    float4 v1 = ((const float4*)src)[lane + 64];
    float ss = v0.x*v0.x + v0.y*v0.y + v0.z*v0.z + v0.w*v0.w
             + v1.x*v1.x + v1.y*v1.y + v1.z*v1.z + v1.w*v1.w;
    #pragma unroll
    for (int off = 32; off > 0; off >>= 1) ss += __shfl_xor(ss, off);
    float inv = 1.0f / fmaxf(sqrtf(ss), 1e-8f);
    // pack 4 normalized floats -> 4 x e4m3 bytes (v_cvt_pk_fp8_f32, OCP fn)
    int w0 = __builtin_amdgcn_cvt_pk_fp8_f32(v0.x * inv, v0.y * inv, 0, false);
    w0     = __builtin_amdgcn_cvt_pk_fp8_f32(v0.z * inv, v0.w * inv, w0, true);
    int w1 = __builtin_amdgcn_cvt_pk_fp8_f32(v1.x * inv, v1.y * inv, 0, false);
    w1     = __builtin_amdgcn_cvt_pk_fp8_f32(v1.z * inv, v1.w * inv, w1, true);
    int* dst = (int*)(zn + (size_t)row * D);
    dst[lane]      = w0;
    dst[lane + 64] = w1;
}

// ---------------- kernel 2: fused symmetric GEMM + exp + row-sum ----------
// Triangular grid: 528 blocks of 256 threads; block -> (bi, bj), bj>=bi.
// fp8 e4m3 operands, 16x16x32_fp8_fp8 MFMA.
//
// ROUND-5 EXPERIMENT: barrier-FREE wave-synchronous pipeline.
// Each wave stages its OWN 64x32 A-half and 64x32 B-half into private LDS
// (2x staging traffic vs shared tiles -- ~135 MB from L2/L3, ~+2 us spread).
// vmcnt retires in issue order, so s_waitcnt vmcnt(4) alone proves the
// wave's own tile-kt DMAs landed: the 16 per-kt {vmcnt + s_barrier} convoy
// points (all 4 waves coupled to the slowest DMA) are GONE. Triple buffer,
// prefetch distance 2 (own in-flight loads: 2 tiles x 4 issues = 8).
// s_setprio(1) around the MFMA cluster: waves are now desynchronized
// (attn-like independent pipelines), the regime where T5 measured +4-7%.
// NOTE (round 4 lesson): no in-kernel cross-block fences -- agent-scope
// release costs ~60 us over 528 blocks; kernel boundary is the cheap sync.
__launch_bounds__(256, 3)
__global__ void gemm_fused(const unsigned char* __restrict__ zn,
                           float* __restrict__ rowsum,
                           float* __restrict__ spos) {
    // buf x wave x {A,B} x [64 rows][32 B] = 48 KB -> 3 blocks/CU
    __shared__ unsigned char L[3][4][2][2048];

    // triangular decode (scalar, <=32 iters)
    int b = blockIdx.x, bi = 0, rowlen = 32;
    while (b >= rowlen) { b -= rowlen; rowlen--; bi++; }
    const int bj = bi + b;
    const int i0 = bi * 128;
    const int j0 = bj * 128;

    const int t = threadIdx.x;
    const int lane = t & 63, wave = t >> 6;
    const int wm = wave & 1, wn = wave >> 1;     // 2x2 waves -> 64x64 each
    const int quad = lane >> 4, l16 = lane & 15;

    // per-wave staging: issue i (i=0,1) covers rows i*32 + (lane>>1),
    // byte col (lane&1)*16; LDS offset = i*1024 + lane*16 (contiguous:
    // global_load_lds dest = wave-uniform base + lane*16)
    const int srow = lane >> 1;
    const int scol = (lane & 1) * 16;
    const unsigned char* gA = zn + (size_t)(i0 + wm * 64 + srow) * D + scol;
    const unsigned char* gB = zn + (size_t)(j0 + wn * 64 + srow) * D + scol;

#define STAGE(bufidx, ko) do {                                                               \
    __builtin_amdgcn_global_load_lds(AS_GLOBAL(gA + (ko)),                                   \
        AS_LDS(&L[bufidx][wave][0][lane * 16]),        16, 0, 0);                            \
    __builtin_amdgcn_global_load_lds(AS_GLOBAL(gA + (ko) + 32 * D),                          \
        AS_LDS(&L[bufidx][wave][0][1024 + lane * 16]), 16, 0, 0);                            \
    __builtin_amdgcn_global_load_lds(AS_GLOBAL(gB + (ko)),                                   \
        AS_LDS(&L[bufidx][wave][1][lane * 16]),        16, 0, 0);                            \
    __builtin_amdgcn_global_load_lds(AS_GLOBAL(gB + (ko) + 32 * D),                          \
        AS_LDS(&L[bufidx][wave][1][1024 + lane * 16]), 16, 0, 0);                            \
} while (0)

    floatx4 acc[4][4] = {};

    // prologue: stage k-tiles 0 and 1 into buffers 0 and 1 (8 loads in flight)
    STAGE(0, 0);
    STAGE(1, 32);

    #pragma unroll
    for (int kt = 0; kt < 16; ++kt) {
        const int cur = kt % 3;
        // own tile-kt DMAs retired (tile kt+1's 4 may stay in flight; after
        // the STAGE below, tile kt+2's 4 join them -> steady state 8)
        if (kt < 15) __builtin_amdgcn_s_waitcnt(WAITCNT_VM(4));
        else         __builtin_amdgcn_s_waitcnt(WAITCNT_VM(0));
        __asm__ volatile("" ::: "memory");       // no LDS-read hoisting
        if (kt < 14) STAGE((kt + 2) % 3, (kt + 2) * 32);
        long af[4], bf[4];
        #pragma unroll
        for (int tm = 0; tm < 4; ++tm)
            af[tm] = *(const long*)(&L[cur][wave][0][(tm * 16 + l16) * 32 + quad * 8]);
        #pragma unroll
        for (int tn = 0; tn < 4; ++tn)
            bf[tn] = *(const long*)(&L[cur][wave][1][(tn * 16 + l16) * 32 + quad * 8]);
        __builtin_amdgcn_s_setprio(1);
        #pragma unroll
        for (int tm = 0; tm < 4; ++tm)
            #pragma unroll
            for (int tn = 0; tn < 4; ++tn)
                acc[tm][tn] = __builtin_amdgcn_mfma_f32_16x16x32_fp8_fp8(
                    af[tm], bf[tn], acc[tm][tn], 0, 0, 0);
        __builtin_amdgcn_s_setprio(0);
    }
#undef STAGE

    // epilogue: e = exp(2s). Row sums -> rows I; column sums -> rows J
    // (off-diagonal tiles; S symmetric).
    float cs[4] = {0.f, 0.f, 0.f, 0.f};
    #pragma unroll
    for (int tm = 0; tm < 4; ++tm) {
        float rs[4] = {0.f, 0.f, 0.f, 0.f};
        #pragma unroll
        for (int tn = 0; tn < 4; ++tn)
            #pragma unroll
            for (int r = 0; r < 4; ++r) {
                float e = exp2f(acc[tm][tn][r] * EXP2_SCALE);
                rs[r] += e;
                cs[tn] += e;
            }
        #pragma unroll
        for (int r = 0; r < 4; ++r) {
            float v = rs[r];
            v += __shfl_xor(v, 1);
            v += __shfl_xor(v, 2);
            v += __shfl_xor(v, 4);
            v += __shfl_xor(v, 8);
            if (l16 == 0) {
                int gi = i0 + wm*64 + tm*16 + quad*4 + r;
                atomicAdd(&rowsum[gi], v);
            }
        }
    }
    if (bi != bj) {
        #pragma unroll
        for (int tn = 0; tn < 4; ++tn) {
            float v = cs[tn];
            v += __shfl_xor(v, 16);
            v += __shfl_xor(v, 32);
            if (quad == 0) {
                int gj = j0 + wn*64 + tn*16 + l16;
                atomicAdd(&rowsum[gj], v);
            }
        }
    }
    // positive pairs (j = i + 2048) live exactly in blocks bj == bi+16
    if (bj == bi + 16) {
        #pragma unroll
        for (int tm = 0; tm < 4; ++tm)
            #pragma unroll
            for (int tn = 0; tn < 4; ++tn)
                #pragma unroll
                for (int r = 0; r < 4; ++r) {
                    int li = wm*64 + tm*16 + quad*4 + r;   // local row
                    int lj = wn*64 + tn*16 + l16;          // local col
                    if (li == lj) {
                        float s = acc[tm][tn][r];
                        spos[i0 + li]         = s;
                        spos[i0 + li + BHALF] = s;
                    }
                }
    }
}

// ---------------- kernel 3: final loss ----------------
__global__ void finalize_kernel(const float* __restrict__ rowsum,
                                const float* __restrict__ spos,
                                float* __restrict__ out) {
    int t = threadIdx.x;                         // 1024 threads, 1 block
    float acc = 0.f;
    for (int i = t; i < N_TOT; i += 1024) {
        float sp = spos[i];
        float denom = rowsum[i] - E2 + exp2f(sp * EXP2_SCALE);
        acc += __logf(denom) - 2.0f * sp;
    }
    #pragma unroll
    for (int off = 32; off > 0; off >>= 1) acc += __shfl_xor(acc, off);
    __shared__ float red[16];
    if ((t & 63) == 0) red[t >> 6] = acc;
    __syncthreads();
    if (t == 0) {
        float s = 0.f;
        #pragma unroll
        for (int w = 0; w < 16; ++w) s += red[w];
        out[0] = s / (float)N_TOT;
    }
}

extern "C" void kernel_launch(void* const* d_in, const int* in_sizes, int n_in,
                              void* d_out, int out_size, void* d_ws, size_t ws_size,
                              hipStream_t stream) {
    const float* z_i = (const float*)d_in[0];
    const float* z_j = (const float*)d_in[1];
    float* out = (float*)d_out;

    char* ws = (char*)d_ws;
    unsigned char* zn = (unsigned char*)ws;                       // 2 MB
    float* rowsum = (float*)(ws + (size_t)N_TOT * D);             // 16 KB
    float* spos   = rowsum + N_TOT;                               // 16 KB

    normalize_kernel<<<N_TOT / 4, 256, 0, stream>>>(z_i, z_j, zn, rowsum);
    gemm_fused<<<(32 * 33) / 2, 256, 0, stream>>>(zn, rowsum, spos);
    finalize_kernel<<<1, 1024, 0, stream>>>(rowsum, spos, out);
}